// Round 4
// baseline (417.838 us; speedup 1.0000x reference)
//
#include <hip/hip_runtime.h>
#include <hip/hip_bf16.h>

typedef __attribute__((ext_vector_type(4))) float  f32x4;
typedef __attribute__((ext_vector_type(8))) short  bf16x8;
typedef unsigned short u16;

#define ALPHA 0.2f
#define NN 8192
#define FF 128
#define LOG2E 1.4426950408889634f

__device__ __forceinline__ u16 f2b(float f) {
  __hip_bfloat16 hb = __float2bfloat16(f);
  return *reinterpret_cast<u16*>(&hb);
}

// ---------- K0: convert x -> bf16 (xb), W -> bf16 transposed (WTb) ----------
extern "C" __global__ void __launch_bounds__(256)
wt_cvt(const float* __restrict__ x, const float* __restrict__ Wm,
       u16* __restrict__ xb, u16* __restrict__ WTb) {
  const int id = blockIdx.x * 256 + threadIdx.x;
  if (blockIdx.x < 2048) {                 // x: 2M elems, 4 per thread
    const f32x4 v = *(const f32x4*)(x + (size_t)id * 4);
    uint2 p;
    p.x = f2b(v.x) | ((unsigned)f2b(v.y) << 16);
    p.y = f2b(v.z) | ((unsigned)f2b(v.w) << 16);
    *(uint2*)(xb + (size_t)id * 4) = p;
  } else {                                  // WT: 32768 elems, 1 per thread
    const int o = id - 2048 * 256;          // o = c*256 + k
    const int c = o >> 8, k = o & 255;
    WTb[o] = f2b(Wm[k * 128 + c]);
  }
}

// ---------- K1: h = x@W via MFMA; write hT2 (fragment-tiled bf16), s1l, s2l --
// hT2 layout: elem(jblk, c, jw) at (jblk*128 + c)*32 + jw, jblk=j>>5, jw=j&31.
// A wave B-fragment (16 c-rows x 32 j) is then 1 KB fully contiguous.
extern "C" __global__ void __launch_bounds__(256)
gat_h(const u16* __restrict__ xb, const u16* __restrict__ WTb,
      const float* __restrict__ av, u16* __restrict__ hT2,
      float* __restrict__ s1v, float* __restrict__ s2v) {
  __shared__ float hs[16][128];
  const int t = threadIdx.x, lane = t & 63, wv = t >> 6;
  const int i0 = blockIdx.x * 16;
  const int fr = lane & 15, kg = lane >> 4;

  f32x4 acc0 = {0.f,0.f,0.f,0.f}, acc1 = {0.f,0.f,0.f,0.f};
  const u16* xp  = xb  + (size_t)(i0 + fr) * 256 + kg * 8;
  const u16* b0p = WTb + (size_t)(wv * 32 + fr) * 256 + kg * 8;
  const u16* b1p = b0p + 16 * 256;
#pragma unroll
  for (int ks = 0; ks < 8; ++ks) {
    const bf16x8 A  = *(const bf16x8*)(xp  + ks * 32);
    const bf16x8 B0 = *(const bf16x8*)(b0p + ks * 32);
    const bf16x8 B1 = *(const bf16x8*)(b1p + ks * 32);
    acc0 = __builtin_amdgcn_mfma_f32_16x16x32_bf16(A, B0, acc0, 0, 0, 0);
    acc1 = __builtin_amdgcn_mfma_f32_16x16x32_bf16(A, B1, acc1, 0, 0, 0);
  }
#pragma unroll
  for (int r = 0; r < 4; ++r) {            // C/D: row=(lane>>4)*4+r, col=lane&15
    hs[kg * 4 + r][wv * 32 + fr]      = acc0[r];
    hs[kg * 4 + r][wv * 32 + 16 + fr] = acc1[r];
  }
  __syncthreads();

  { // hT2 write: 16 nodes of this block = jw (i0&31)+0..15 of jblk i0>>5
    const int c = t >> 1, rr = (t & 1) * 8;
    u16 u[8];
#pragma unroll
    for (int m = 0; m < 8; ++m) u[m] = f2b(hs[rr + m][c]);
    *(uint4*)(hT2 + ((size_t)(i0 >> 5) * 128 + c) * 32 + (i0 & 31) + rr) =
        *(const uint4*)u;
  }
  { // s1/s2 (pre-scaled by log2e)
    const int r = t >> 4, q = t & 15;
    float p1 = 0.f, p2 = 0.f;
#pragma unroll
    for (int m = 0; m < 8; ++m) {
      const int c = q * 8 + m;
      const float hv = hs[r][c];
      p1 = fmaf(hv, av[c], p1);
      p2 = fmaf(hv, av[128 + c], p2);
    }
    p1 += __shfl_xor(p1, 1); p1 += __shfl_xor(p1, 2);
    p1 += __shfl_xor(p1, 4); p1 += __shfl_xor(p1, 8);
    p2 += __shfl_xor(p2, 1); p2 += __shfl_xor(p2, 2);
    p2 += __shfl_xor(p2, 4); p2 += __shfl_xor(p2, 8);
    if (q == 0) { s1v[i0 + r] = p1 * LOG2E; s2v[i0 + r] = p2 * LOG2E; }
  }
}

// ---------- K2: barrier-free, LDS-free main loop --------------------------
// 512 blocks x 256 thr (4 waves). Block: 16 rows x all j. Wave ks owns the
// k-slice j = it*128 + ks*32 of every chunk; A-fragment generated per-lane in
// registers (row=lane&15, k=(lane>>4)*8+e); B-fragments loaded coalesced from
// fragment-tiled hT2 (L2-resident). acc held in regs across all 64 chunks;
// single 4-way LDS reduce at the end.
#define MM(BB, AA) AA = __builtin_amdgcn_mfma_f32_16x16x32_bf16(af, BB, AA, 0, 0, 0)

extern "C" __global__ void __launch_bounds__(256, 4)
gat_main(const float* __restrict__ adj, const u16* __restrict__ hT2,
         const float* __restrict__ s1l, const float* __restrict__ s2l,
         float* __restrict__ out) {
  __shared__ float accp[4][16][132];   // 33.8 KB
  __shared__ float denp[4][16];

  const int t = threadIdx.x, lane = t & 63, ks = t >> 6;
  const int fr = lane & 15, kg = lane >> 4;
  const int i0 = blockIdx.x * 16;

  const float s1i = s1l[i0 + fr];
  const float* adjp = adj + (size_t)(i0 + fr) * NN + ks * 32 + kg * 8;
  const float* s2p  = s2l + ks * 32 + kg * 8;
  const u16*   hp   = hT2 + ks * 4096 + fr * 32 + kg * 8;

  f32x4 acc0 = {0,0,0,0}, acc1 = {0,0,0,0}, acc2 = {0,0,0,0}, acc3 = {0,0,0,0};
  f32x4 acc4 = {0,0,0,0}, acc5 = {0,0,0,0}, acc6 = {0,0,0,0}, acc7 = {0,0,0,0};
  float den = 0.f;

  // prefetch chunk 0 adj/s2
  f32x4 a0 = *(const f32x4*)(adjp);
  f32x4 a1 = *(const f32x4*)(adjp + 4);
  f32x4 z0 = *(const f32x4*)(s2p);
  f32x4 z1 = *(const f32x4*)(s2p + 4);

  for (int it = 0; it < 64; ++it) {
    // B fragments for this chunk: 8 x 1KB coalesced wave-reads, batch-issued
    const u16* hb = hp + it * 16384;
    const bf16x8 b0 = *(const bf16x8*)(hb);
    const bf16x8 b1 = *(const bf16x8*)(hb + 512);
    const bf16x8 b2 = *(const bf16x8*)(hb + 1024);
    const bf16x8 b3 = *(const bf16x8*)(hb + 1536);
    const bf16x8 b4 = *(const bf16x8*)(hb + 2048);
    const bf16x8 b5 = *(const bf16x8*)(hb + 2560);
    const bf16x8 b6 = *(const bf16x8*)(hb + 3072);
    const bf16x8 b7 = *(const bf16x8*)(hb + 3584);
    __builtin_amdgcn_sched_barrier(0);   // keep B loads issued before exp

    // A fragment: w = adj * exp2(lrelu(s1l+s2l))  (adj is exactly 0/1)
    bf16x8 af;
    float dstep = 0.f;
#pragma unroll
    for (int e = 0; e < 8; ++e) {
      const float adv = (e < 4) ? a0[e] : a1[e - 4];
      const float tz  = s1i + ((e < 4) ? z0[e] : z1[e - 4]);
      const float fz  = fmaxf(tz, ALPHA * tz);
      const float w8  = adv * exp2f(fz);
      dstep += w8;
      af[e] = (short)f2b(w8);
    }
    den += dstep;

    // prefetch next chunk's adj/s2 (distance-1; clamp keeps last read in-bounds)
    const int itn = it < 63 ? it + 1 : 63;
    const float* an = adjp + itn * 128;
    a0 = *(const f32x4*)(an);
    a1 = *(const f32x4*)(an + 4);
    const float* zn = s2p + itn * 128;
    z0 = *(const f32x4*)(zn);
    z1 = *(const f32x4*)(zn + 4);
    __builtin_amdgcn_sched_barrier(0);   // keep prefetch before MFMA cluster

    MM(b0, acc0); MM(b1, acc1); MM(b2, acc2); MM(b3, acc3);
    MM(b4, acc4); MM(b5, acc5); MM(b6, acc6); MM(b7, acc7);
  }

  // den: lanes {l, l+16, l+32, l+48} share row fr, disjoint j
  den += __shfl_xor(den, 16);
  den += __shfl_xor(den, 32);
  if (lane < 16) denp[ks][fr] = den;

  // C/D layout: row=(lane>>4)*4+r, col=f*16+(lane&15)
#define STACC(F, AA) _Pragma("unroll") \
  for (int r = 0; r < 4; ++r) accp[ks][kg * 4 + r][F * 16 + fr] = AA[r];
  STACC(0, acc0) STACC(1, acc1) STACC(2, acc2) STACC(3, acc3)
  STACC(4, acc4) STACC(5, acc5) STACC(6, acc6) STACC(7, acc7)
#undef STACC

  __syncthreads();

  { // 4-way reduce + softmax divide + coalesced store
    const int row = t >> 4;
    const int c0  = (t & 15) * 8;
    const float dv = denp[0][row] + denp[1][row] + denp[2][row] + denp[3][row];
    f32x4 sA = {0,0,0,0}, sB = {0,0,0,0};
#pragma unroll
    for (int w = 0; w < 4; ++w) {
      sA += *(const f32x4*)&accp[w][row][c0];
      sB += *(const f32x4*)&accp[w][row][c0 + 4];
    }
    const float inv = 1.f / dv;
    sA *= inv; sB *= inv;
    float* op = out + (size_t)(i0 + row) * FF + c0;
    *(f32x4*)op       = sA;
    *(f32x4*)(op + 4) = sB;
  }
}

extern "C" void kernel_launch(void* const* d_in, const int* in_sizes, int n_in,
                              void* d_out, int out_size, void* d_ws, size_t ws_size,
                              hipStream_t stream) {
  const float* x   = (const float*)d_in[0];
  const float* adj = (const float*)d_in[1];
  const float* Wm  = (const float*)d_in[2];
  const float* av  = (const float*)d_in[3];
  float* out = (float*)d_out;

  char* ws = (char*)d_ws;
  u16*   hT2 = (u16*)(ws);                       // 2 MB
  float* s1v = (float*)(ws + 2097152);           // 32 KB
  float* s2v = (float*)(ws + 2129920);           // 32 KB
  u16*   xb  = (u16*)(ws + 2162688);             // 4 MB
  u16*   WTb = (u16*)(ws + 6356992);             // 64 KB

  wt_cvt  <<<2176, 256, 0, stream>>>(x, Wm, xb, WTb);
  gat_h   <<<NN / 16, 256, 0, stream>>>(xb, WTb, av, hT2, s1v, s2v);
  gat_main<<<NN / 16, 256, 0, stream>>>(adj, hT2, s1v, s2v, out);
}